// Round 1
// baseline (412.140 us; speedup 1.0000x reference)
//
#include <hip/hip_runtime.h>

// out[b,i] = sum_{lag=0..7} x[b, lag*2048 + i] * weight[i, lag*2048 + i]
// Pure memory-bound streaming: 256 MiB x-read + 32 MiB out-write + 64 KB diag.

#define N_VARS 2048
#define P      8
#define BATCH  4096
#define ROW    (N_VARS * P)   // 16384 floats per x row / weight row
#define I4     (N_VARS / 4)   // 512 float4 per output row

// Step 1: gather the 16K diagonal weights into wd[lag*N_VARS + i]
__global__ void extract_diag_kernel(const float* __restrict__ w,
                                    float* __restrict__ wd) {
    int idx = blockIdx.x * blockDim.x + threadIdx.x;   // 0 .. 16383
    if (idx < N_VARS * P) {
        int lag = idx >> 11;            // idx / 2048
        int i   = idx & (N_VARS - 1);   // idx % 2048
        // w[i, lag*N_VARS + i]
        wd[idx] = w[(size_t)i * ROW + (size_t)lag * N_VARS + i];
    }
}

// Step 2: streaming diagonal contraction, float4-vectorized.
__global__ __launch_bounds__(256)
void diag_linear_kernel(const float4* __restrict__ x,
                        const float4* __restrict__ wd,
                        float4* __restrict__ out) {
    const size_t total  = (size_t)BATCH * I4;           // 2,097,152 float4 outputs
    const size_t stride = (size_t)gridDim.x * blockDim.x;
    for (size_t idx = (size_t)blockIdx.x * blockDim.x + threadIdx.x;
         idx < total; idx += stride) {
        const int    i4 = (int)(idx & (I4 - 1));        // float4 column
        const size_t b  = idx >> 9;                     // batch row (idx / 512)
        const float4* __restrict__ xrow = x + b * (ROW / 4);
        float4 acc = make_float4(0.f, 0.f, 0.f, 0.f);
        #pragma unroll
        for (int lag = 0; lag < P; ++lag) {
            const float4 xv = xrow[lag * I4 + i4];
            const float4 wv = wd[lag * I4 + i4];        // 64 KB total -> L1/L2 hit
            acc.x = fmaf(xv.x, wv.x, acc.x);
            acc.y = fmaf(xv.y, wv.y, acc.y);
            acc.z = fmaf(xv.z, wv.z, acc.z);
            acc.w = fmaf(xv.w, wv.w, acc.w);
        }
        out[idx] = acc;
    }
}

// Fallback if d_ws is too small: read the diagonal weights directly (cached).
__global__ __launch_bounds__(256)
void diag_linear_direct_kernel(const float* __restrict__ x,
                               const float* __restrict__ w,
                               float* __restrict__ out) {
    const size_t total  = (size_t)BATCH * N_VARS;
    const size_t stride = (size_t)gridDim.x * blockDim.x;
    for (size_t idx = (size_t)blockIdx.x * blockDim.x + threadIdx.x;
         idx < total; idx += stride) {
        const int    i = (int)(idx & (N_VARS - 1));
        const size_t b = idx >> 11;
        const float* __restrict__ xrow = x + b * ROW;
        float acc = 0.f;
        #pragma unroll
        for (int lag = 0; lag < P; ++lag) {
            acc = fmaf(xrow[lag * N_VARS + i],
                       w[(size_t)i * ROW + (size_t)lag * N_VARS + i], acc);
        }
        out[idx] = acc;
    }
}

extern "C" void kernel_launch(void* const* d_in, const int* in_sizes, int n_in,
                              void* d_out, int out_size, void* d_ws, size_t ws_size,
                              hipStream_t stream) {
    const float* x = (const float*)d_in[0];   // (BATCH, ROW)
    const float* w = (const float*)d_in[1];   // (N_VARS, ROW)
    float* out = (float*)d_out;               // (BATCH, N_VARS)

    if (ws_size >= (size_t)(N_VARS * P) * sizeof(float)) {
        float* wd = (float*)d_ws;
        extract_diag_kernel<<<(N_VARS * P + 255) / 256, 256, 0, stream>>>(w, wd);
        diag_linear_kernel<<<2048, 256, 0, stream>>>(
            (const float4*)x, (const float4*)wd, (float4*)out);
    } else {
        diag_linear_direct_kernel<<<2048, 256, 0, stream>>>(x, w, out);
    }
}